// Round 7
// baseline (735.110 us; speedup 1.0000x reference)
//
#include <hip/hip_runtime.h>
#include <math.h>

// ---------------------------------------------------------------------------
// GCNRecommender: 3x GCNConv (D=64) + linear head. N=300K nodes, E=1.2M edges.
// R11: all LDS-fed GEMMs plateau at 76-86us -- the per-CU LDS pipe is ~2.5x
// oversubscribed vs VALU (10 ds_read_b128 per kg per wave, CU-shared). New
// GEMM: ROW-PER-THREAD, NO LDS, NO BARRIERS. Each thread holds its X row in
// 16 float4 regs (loaded once); W addresses are wave-uniform -> compiler
// emits s_load (scalar K$ pipe, off both LDS and VMEM); two 32-col halves
// keep acc at 8 float4. Only VMEM: 16 up-front X loads + 16 stores ->
// nothing for the scheduler to hoist, spill-proof. Roofline: VALU 15.6us,
// HBM ~24us -> expect ~25-40us/GEMM. Gather/CSR unchanged. All fp32.
// ---------------------------------------------------------------------------

// ---- CSR build -------------------------------------------------------------

__global__ void k_hist(const int* __restrict__ col, int* __restrict__ cnt, int e) {
    int i = blockIdx.x * blockDim.x + threadIdx.x;
    if (i < e) atomicAdd(&cnt[col[i]], 1);
}

// exclusive scan, 1024 elems/block (256 thr x 4)
__global__ void k_scan1(const int* __restrict__ cnt, int* __restrict__ offs,
                        int* __restrict__ bsum, int n) {
    __shared__ int s[256];
    const int t = threadIdx.x;
    const int base = blockIdx.x * 1024 + t * 4;
    int v[4], sum = 0;
    #pragma unroll
    for (int k = 0; k < 4; ++k) {
        v[k] = (base + k < n) ? cnt[base + k] : 0;
        sum += v[k];
    }
    s[t] = sum;
    __syncthreads();
    #pragma unroll
    for (int off = 1; off < 256; off <<= 1) {
        int x = (t >= off) ? s[t - off] : 0;
        __syncthreads();
        s[t] += x;
        __syncthreads();
    }
    int run = s[t] - sum;
    #pragma unroll
    for (int k = 0; k < 4; ++k) {
        if (base + k < n) offs[base + k] = run;
        run += v[k];
    }
    if (t == 255) bsum[blockIdx.x] = s[255];
}

__global__ void k_scan2(int* __restrict__ bsum, int nb) {
    __shared__ int s[512];
    const int t = threadIdx.x;
    int v = (t < nb) ? bsum[t] : 0;
    s[t] = v;
    __syncthreads();
    #pragma unroll
    for (int off = 1; off < 512; off <<= 1) {
        int x = (t >= off) ? s[t - off] : 0;
        __syncthreads();
        s[t] += x;
        __syncthreads();
    }
    if (t < nb) bsum[t] = s[t] - v;
}

__global__ void k_scan3(int* __restrict__ offs, const int* __restrict__ bsum,
                        int n, int e) {
    int i = blockIdx.x * blockDim.x + threadIdx.x;
    if (i < n) offs[i] += bsum[i >> 10];
    if (i == 0) offs[n] = e;
}

__global__ void k_fill(const int* __restrict__ row, const int* __restrict__ col,
                       const int* __restrict__ offs, int* __restrict__ cur,
                       int* __restrict__ elist, int e) {
    int i = blockIdx.x * blockDim.x + threadIdx.x;
    if (i < e) {
        int c = col[i];
        int pos = offs[c] + atomicAdd(&cur[c], 1);
        elist[pos] = row[i];
    }
}

__global__ void k_dinv(const int* __restrict__ cnt, float* __restrict__ dinv, int n) {
    int i = blockIdx.x * blockDim.x + threadIdx.x;
    if (i < n) dinv[i] = 1.0f / sqrtf((float)(cnt[i] + 1));  // +1 self-loop
}

// ---- GEMM: Y[r,:] = X[r,:] @ W  (row-per-thread, LDS-free) -----------------
// X source: (ut!=null) ? embedding tables (conv1) : dense X.
// Thread owns one row: X row in 16 float4 regs; loops 2 col-halves (32 cols,
// 8 float4 accs). W reads are wave-uniform -> scalar loads (K$ pipe).
// Epilogue: dinv!=null -> Y = dinv[row]*y (conv; bias+relu in gather)
//           dinv==null -> Y = y + bias   (linear head)

// one W row (4 consecutive k? no: one k), 32 cols starting at coff
#define KROW(XS, WOFF)                                                        \
    {                                                                         \
        const float4* wp = (const float4*)(W + (WOFF));                       \
        float4 w0 = wp[0], w1 = wp[1], w2 = wp[2], w3 = wp[3];                \
        float4 w4 = wp[4], w5 = wp[5], w6 = wp[6], w7 = wp[7];                \
        a0.x = fmaf(XS, w0.x, a0.x); a0.y = fmaf(XS, w0.y, a0.y);             \
        a0.z = fmaf(XS, w0.z, a0.z); a0.w = fmaf(XS, w0.w, a0.w);             \
        a1.x = fmaf(XS, w1.x, a1.x); a1.y = fmaf(XS, w1.y, a1.y);             \
        a1.z = fmaf(XS, w1.z, a1.z); a1.w = fmaf(XS, w1.w, a1.w);             \
        a2.x = fmaf(XS, w2.x, a2.x); a2.y = fmaf(XS, w2.y, a2.y);             \
        a2.z = fmaf(XS, w2.z, a2.z); a2.w = fmaf(XS, w2.w, a2.w);             \
        a3.x = fmaf(XS, w3.x, a3.x); a3.y = fmaf(XS, w3.y, a3.y);             \
        a3.z = fmaf(XS, w3.z, a3.z); a3.w = fmaf(XS, w3.w, a3.w);             \
        a4.x = fmaf(XS, w4.x, a4.x); a4.y = fmaf(XS, w4.y, a4.y);             \
        a4.z = fmaf(XS, w4.z, a4.z); a4.w = fmaf(XS, w4.w, a4.w);             \
        a5.x = fmaf(XS, w5.x, a5.x); a5.y = fmaf(XS, w5.y, a5.y);             \
        a5.z = fmaf(XS, w5.z, a5.z); a5.w = fmaf(XS, w5.w, a5.w);             \
        a6.x = fmaf(XS, w6.x, a6.x); a6.y = fmaf(XS, w6.y, a6.y);             \
        a6.z = fmaf(XS, w6.z, a6.z); a6.w = fmaf(XS, w6.w, a6.w);             \
        a7.x = fmaf(XS, w7.x, a7.x); a7.y = fmaf(XS, w7.y, a7.y);             \
        a7.z = fmaf(XS, w7.z, a7.z); a7.w = fmaf(XS, w7.w, a7.w);             \
    }

// one k-group (4 k values) against col range [coff, coff+32)
#define KGRP(XK, KG_)                                                         \
    KROW((XK).x, ((KG_) * 4 + 0) * 64 + coff)                                 \
    KROW((XK).y, ((KG_) * 4 + 1) * 64 + coff)                                 \
    KROW((XK).z, ((KG_) * 4 + 2) * 64 + coff)                                 \
    KROW((XK).w, ((KG_) * 4 + 3) * 64 + coff)

__launch_bounds__(256, 2)
__global__ void k_gemm(const float* __restrict__ X,
                       const int* __restrict__ uid, const int* __restrict__ iid,
                       const float* __restrict__ ut, const float* __restrict__ it,
                       const float* __restrict__ W, const float* __restrict__ bias,
                       float* __restrict__ Y, const float* __restrict__ dinv,
                       int n, int u) {
    const int row = blockIdx.x * 256 + threadIdx.x;
    if (row >= n) return;                 // no barriers in kernel: safe

    const float* src;
    if (ut != nullptr)
        src = (row < u) ? (ut + (size_t)uid[row] * 64)
                        : (it + (size_t)iid[row - u] * 64);
    else
        src = X + (size_t)row * 64;

    const float4* s4 = (const float4*)src;
    float4 x[16];
    #pragma unroll
    for (int i = 0; i < 16; ++i) x[i] = s4[i];   // whole row in regs, once

    const float ds = (dinv != nullptr) ? dinv[row] : 0.f;
    float* yrow = Y + (size_t)row * 64;

    #pragma unroll 1
    for (int c2 = 0; c2 < 2; ++c2) {
        const int coff = c2 * 32;                 // wave-uniform
        float4 a0 = make_float4(0.f, 0.f, 0.f, 0.f);
        float4 a1 = make_float4(0.f, 0.f, 0.f, 0.f);
        float4 a2 = make_float4(0.f, 0.f, 0.f, 0.f);
        float4 a3 = make_float4(0.f, 0.f, 0.f, 0.f);
        float4 a4 = make_float4(0.f, 0.f, 0.f, 0.f);
        float4 a5 = make_float4(0.f, 0.f, 0.f, 0.f);
        float4 a6 = make_float4(0.f, 0.f, 0.f, 0.f);
        float4 a7 = make_float4(0.f, 0.f, 0.f, 0.f);

        KGRP(x[0], 0)   KGRP(x[1], 1)   KGRP(x[2], 2)   KGRP(x[3], 3)
        KGRP(x[4], 4)   KGRP(x[5], 5)   KGRP(x[6], 6)   KGRP(x[7], 7)
        KGRP(x[8], 8)   KGRP(x[9], 9)   KGRP(x[10], 10) KGRP(x[11], 11)
        KGRP(x[12], 12) KGRP(x[13], 13) KGRP(x[14], 14) KGRP(x[15], 15)

        if (dinv != nullptr) {
            a0.x *= ds; a0.y *= ds; a0.z *= ds; a0.w *= ds;
            a1.x *= ds; a1.y *= ds; a1.z *= ds; a1.w *= ds;
            a2.x *= ds; a2.y *= ds; a2.z *= ds; a2.w *= ds;
            a3.x *= ds; a3.y *= ds; a3.z *= ds; a3.w *= ds;
            a4.x *= ds; a4.y *= ds; a4.z *= ds; a4.w *= ds;
            a5.x *= ds; a5.y *= ds; a5.z *= ds; a5.w *= ds;
            a6.x *= ds; a6.y *= ds; a6.z *= ds; a6.w *= ds;
            a7.x *= ds; a7.y *= ds; a7.z *= ds; a7.w *= ds;
        } else {
            const float4* bp = (const float4*)(bias + coff);  // uniform
            float4 b0 = bp[0], b1 = bp[1], b2 = bp[2], b3 = bp[3];
            float4 b4 = bp[4], b5 = bp[5], b6 = bp[6], b7 = bp[7];
            a0.x += b0.x; a0.y += b0.y; a0.z += b0.z; a0.w += b0.w;
            a1.x += b1.x; a1.y += b1.y; a1.z += b1.z; a1.w += b1.w;
            a2.x += b2.x; a2.y += b2.y; a2.z += b2.z; a2.w += b2.w;
            a3.x += b3.x; a3.y += b3.y; a3.z += b3.z; a3.w += b3.w;
            a4.x += b4.x; a4.y += b4.y; a4.z += b4.z; a4.w += b4.w;
            a5.x += b5.x; a5.y += b5.y; a5.z += b5.z; a5.w += b5.w;
            a6.x += b6.x; a6.y += b6.y; a6.z += b6.z; a6.w += b6.w;
            a7.x += b7.x; a7.y += b7.y; a7.z += b7.z; a7.w += b7.w;
        }

        float4* yp = (float4*)(yrow + coff);
        yp[0] = a0; yp[1] = a1; yp[2] = a2; yp[3] = a3;
        yp[4] = a4; yp[5] = a5; yp[6] = a6; yp[7] = a7;
    }
}

// ---- gather: 16 lanes per node (4 nodes/wave, 16 nodes/block).
// OUT[c,:] = f( dinv[c] * (sum_{r in in(c)} Yn[r,:] + Yn[c,:]) + b ),
// f = relu (conv1/conv2 outputs) or identity (conv3 output).
// Neighbor loop unrolled x4: 4 independent row loads in flight.
__launch_bounds__(256)
__global__ void k_gather(const int* __restrict__ offs, const int* __restrict__ elist,
                         const float* __restrict__ dinv, const float4* __restrict__ Yn4,
                         const float4* __restrict__ b4, float4* __restrict__ OUT4,
                         int n, int relu_out) {
    const int t = threadIdx.x;
    const int nid = blockIdx.x * 16 + (t >> 4);  // this 16-lane group's node
    const int q = t & 15;                        // float4 column group
    const int gbase = t & 48;                    // first lane of this group
    if (nid >= n) return;

    const int beg = offs[nid];
    const int end = offs[nid + 1];
    const int deg = end - beg;

    // Issue independent loads early: self row, dinv, bias, first 16 edge idx.
    float4 self = Yn4[(size_t)nid * 16 + q];
    float dc = dinv[nid];
    float4 bb = b4[q];
    int eidx = (q < deg) ? elist[beg + q] : 0;   // safe default row 0

    // wave-wide max degree (groups diverge only in predicates, not trip count)
    int m = deg;
    m = max(m, __shfl_xor(m, 16, 64));
    m = max(m, __shfl_xor(m, 32, 64));
    m = min(m, 16);

    float4 acc = make_float4(0.f, 0.f, 0.f, 0.f);
    int j = 0;
    for (; j + 4 <= m; j += 4) {
        int r0 = __shfl(eidx, gbase + j + 0, 64);
        int r1 = __shfl(eidx, gbase + j + 1, 64);
        int r2 = __shfl(eidx, gbase + j + 2, 64);
        int r3 = __shfl(eidx, gbase + j + 3, 64);
        float4 v0 = Yn4[(size_t)r0 * 16 + q];    // 4 loads in flight
        float4 v1 = Yn4[(size_t)r1 * 16 + q];
        float4 v2 = Yn4[(size_t)r2 * 16 + q];
        float4 v3 = Yn4[(size_t)r3 * 16 + q];
        if (j + 0 < deg) { acc.x += v0.x; acc.y += v0.y; acc.z += v0.z; acc.w += v0.w; }
        if (j + 1 < deg) { acc.x += v1.x; acc.y += v1.y; acc.z += v1.z; acc.w += v1.w; }
        if (j + 2 < deg) { acc.x += v2.x; acc.y += v2.y; acc.z += v2.z; acc.w += v2.w; }
        if (j + 3 < deg) { acc.x += v3.x; acc.y += v3.y; acc.z += v3.z; acc.w += v3.w; }
    }
    for (; j < m; ++j) {
        int r = __shfl(eidx, gbase + j, 64);
        float4 v = Yn4[(size_t)r * 16 + q];
        if (j < deg) { acc.x += v.x; acc.y += v.y; acc.z += v.z; acc.w += v.w; }
    }
    // rare tail (deg > 16): ~0 nodes for Poisson(4), correctness only
    for (int jj = beg + 16; jj < end; ++jj) {
        int r = elist[jj];
        float4 v = Yn4[(size_t)r * 16 + q];
        acc.x += v.x; acc.y += v.y; acc.z += v.z; acc.w += v.w;
    }

    float4 o;
    o.x = fmaf(dc, acc.x + self.x, bb.x);
    o.y = fmaf(dc, acc.y + self.y, bb.y);
    o.z = fmaf(dc, acc.z + self.z, bb.z);
    o.w = fmaf(dc, acc.w + self.w, bb.w);
    if (relu_out) {
        o.x = fmaxf(o.x, 0.f); o.y = fmaxf(o.y, 0.f);
        o.z = fmaxf(o.z, 0.f); o.w = fmaxf(o.w, 0.f);
    }
    OUT4[(size_t)nid * 16 + q] = o;
}

// ---------------------------------------------------------------------------

extern "C" void kernel_launch(void* const* d_in, const int* in_sizes, int n_in,
                              void* d_out, int out_size, void* d_ws, size_t ws_size,
                              hipStream_t stream) {
    const int*   user_ids = (const int*)d_in[0];
    const int*   item_ids = (const int*)d_in[1];
    const int*   edge     = (const int*)d_in[2];
    const float* ut   = (const float*)d_in[4];
    const float* it   = (const float*)d_in[5];
    const float* W1   = (const float*)d_in[6];
    const float* b1   = (const float*)d_in[7];
    const float* W2   = (const float*)d_in[8];
    const float* b2   = (const float*)d_in[9];
    const float* W3   = (const float*)d_in[10];
    const float* b3   = (const float*)d_in[11];
    const float* linW = (const float*)d_in[12];
    const float* linb = (const float*)d_in[13];

    const int u = in_sizes[0];
    const int iN = in_sizes[1];
    const int e = in_sizes[2] / 2;
    const int n = u + iN;

    // workspace layout
    float* A    = (float*)d_ws;                       // [n,64] node features
    float* dinv = A + (size_t)n * 64;                 // [n]
    int*   cnt  = (int*)(dinv + n);                   // [n]  (reused as cursor)
    int*   offs = cnt + n;                            // [n+1]
    int*   bsum = offs + n + 1;                       // [nb]
    int*   elist = bsum + 1024;                       // [e]
    float* Yn   = (float*)d_out;                      // [n,64] scratch; final out

    const int* erow = edge;
    const int* ecol = edge + e;

    const int B = 256;
    const int nb = (n + 1023) / 1024;

    // ---- CSR build + dinv ----
    hipMemsetAsync(cnt, 0, (size_t)n * sizeof(int), stream);
    k_hist<<<(e + B - 1) / B, B, 0, stream>>>(ecol, cnt, e);
    k_scan1<<<nb, 256, 0, stream>>>(cnt, offs, bsum, n);
    k_scan2<<<1, 512, 0, stream>>>(bsum, nb);
    k_scan3<<<(n + B - 1) / B, B, 0, stream>>>(offs, bsum, n, e);
    k_dinv<<<(n + B - 1) / B, B, 0, stream>>>(cnt, dinv, n);
    hipMemsetAsync(cnt, 0, (size_t)n * sizeof(int), stream);  // cursor
    k_fill<<<(e + B - 1) / B, B, 0, stream>>>(erow, ecol, offs, cnt, elist, e);

    const int gemm_grid = (n + 255) / 256;   // one row per thread
    const int gath_grid = (n + 15) / 16;     // 16 nodes/block

    // conv1 (embed fused into row load)
    k_gemm<<<gemm_grid, B, 0, stream>>>(nullptr, user_ids, item_ids, ut, it,
                                        W1, nullptr, Yn, dinv, n, u);
    k_gather<<<gath_grid, B, 0, stream>>>(offs, elist, dinv, (const float4*)Yn,
                                          (const float4*)b1, (float4*)A, n, 1);
    // conv2 (relu applied at gather1 store)
    k_gemm<<<gemm_grid, B, 0, stream>>>(A, nullptr, nullptr, nullptr, nullptr,
                                        W2, nullptr, Yn, dinv, n, u);
    k_gather<<<gath_grid, B, 0, stream>>>(offs, elist, dinv, (const float4*)Yn,
                                          (const float4*)b2, (float4*)A, n, 1);
    // conv3
    k_gemm<<<gemm_grid, B, 0, stream>>>(A, nullptr, nullptr, nullptr, nullptr,
                                        W3, nullptr, Yn, dinv, n, u);
    k_gather<<<gath_grid, B, 0, stream>>>(offs, elist, dinv, (const float4*)Yn,
                                          (const float4*)b3, (float4*)A, n, 0);
    // mean-pool = identity; linear head -> d_out
    k_gemm<<<gemm_grid, B, 0, stream>>>(A, nullptr, nullptr, nullptr, nullptr,
                                        linW, linb, (float*)d_out, nullptr, n, u);
}